// Round 8
// baseline (247.450 us; speedup 1.0000x reference)
//
#include <hip/hip_runtime.h>
#include <cstdint>
#include <cstddef>

// Problem constants
#define BB 2
#define SS 2048
#define EE 1024
#define HH 16
#define DD 64

typedef __attribute__((ext_vector_type(8))) short short8;           // 16x16x32 A/B frag
typedef __attribute__((ext_vector_type(4))) short shortx4;          // 16x16x16 A/B frag
typedef __attribute__((ext_vector_type(8))) unsigned short ushort8; // 16B vector ld/st
typedef __attribute__((ext_vector_type(4))) unsigned short ush4;    // 8B vector st
typedef __attribute__((ext_vector_type(4))) float floatx4;          // MFMA C/D frag / float4

#define MFMA32(a, b, c) __builtin_amdgcn_mfma_f32_16x16x32_bf16((a), (b), (c), 0, 0, 0)
#define MFMA16(a, b, c) __builtin_amdgcn_mfma_f32_16x16x16bf16_1k((a), (b), (c), 0, 0, 0)

// 0.125 (1/sqrt(64)) * log2(e): folded into Q so attn can use exp2 directly.
#define QSCALE 0.18033688011112042f

// float -> bf16 bits, round-to-nearest-even (same rounding the old k_cvt used,
// so GEMM inputs are bit-identical to the 3-kernel pipeline's).
__device__ __forceinline__ unsigned short f2bf(float f) {
    unsigned int u = __float_as_uint(f);
    u += 0x7fffu + ((u >> 16) & 1u);
    return (unsigned short)(u >> 16);
}

// pack two floats into bf16x2 (round-half-up): 2 adds + 1 v_perm
__device__ __forceinline__ unsigned int pkbf(float a, float b) {
    return __builtin_amdgcn_perm(__float_as_uint(b) + 0x8000u,
                                 __float_as_uint(a) + 0x8000u, 0x07060302u);
}

// ---------------------------------------------------------------------------
// GEMM v6 (R8): fused fp32->bf16 conversion in staging; k_cvt deleted.
// R7 post-mortem: non-attn time invariant ~175us across 5 GEMM-schedule
// variants while individual dispatches moved -> the fixed costs (k_cvt's
// 75 MB HBM round-trip + an extra launch gap) are the removable part.
// Structure: reg-staged pipeline proven in attn v8 -- per phase p:
//   s_barrier                       // buf[p&1] visible; prev reads done
//   issue loads(p+2) -> set[p&1]    // fp32 (or bf16 for OMODE2's A)
//   compute(buf[p&1])               // 8 ds_read_b128 + 16 MFMA32
//   sched_barrier(0)
//   cvt+ds_write set[(p+1)&1] -> buf[(p+1)&1]   // compiler emits counted
//   s_waitcnt lgkmcnt(0)            // vmcnt here; loads(p+2) stay in flight
// Hazards: WAR -- buf[(p+1)&1]'s last readers ran in compute(p-1), and every
// wave consumed those ds_reads (lgkm-waited before its MFMAs) before reaching
// barrier(p). RAW -- writer did lgkmcnt(0) before barrier(p+1). Conversion
// sits in putS (write site), so fp32 stays in regs one phase and the vmcnt
// wait lands at the write, not at issue. Dead wrap loads at the tail are
// register-only; the dead tile-32 write precedes endpgm harmlessly (block-
// private LDS, all computes done).
// A operand: AF32=1 -> fp32 + convert (x,y); AF32=0 -> bf16 passthrough (Aw).
// B operand (weights) is always fp32 + convert.
// OMODE: 0 = bf16 row-major [M][1024], 1 = bf16 V-transposed
//        [b*1024+col][2048], 2 = fp32 row-major [M][1024].
// ---------------------------------------------------------------------------
template <int OMODE, bool AF32>
__device__ __forceinline__ void gemm_fused(
    const void* __restrict__ Av, const float* __restrict__ W,
    const float* __restrict__ bias, void* __restrict__ Cv, float oscale,
    int m0, int n0, unsigned short* As0, unsigned short* As1,
    unsigned short* Bs0, unsigned short* Bs1)
{
    constexpr int K = 1024, N = 1024, LDT = 32;
    const int t = threadIdx.x;
    const int lane = t & 63, w = t >> 6;
    const int q = lane >> 4, c = lane & 15;
    const int wm = w & 1, wn = w >> 1;
    // staging: thread t owns row t/2, k-halves (t&1)*16 of the 128x32 subtile
    const int srow = t >> 1, sk = (t & 1) * 16;

    const float* gAf = (const float*)Av + (size_t)(m0 + srow) * K + sk;
    const unsigned short* gAh =
        (const unsigned short*)Av + (size_t)(m0 + srow) * K + sk;
    const float* gB = W + (size_t)(n0 + srow) * K + sk;
    unsigned short* wA[2] = {As0 + srow * LDT + sk, As1 + srow * LDT + sk};
    unsigned short* wB[2] = {Bs0 + srow * LDT + sk, Bs1 + srow * LDT + sk};

    floatx4 acc[4][4] = {};
    floatx4 rAf[2][4];   // AF32: raw fp32 A staging regs (2 sets)
    ushort8 rAh[2][2];   // !AF32: bf16 A staging regs
    floatx4 rBf[2][4];   // fp32 B staging regs

    auto load = [&](int p, int s) {
        const int np = p & 31;   // wrap -> dead register-only loads at tail
        if constexpr (AF32) {
            const floatx4* g = (const floatx4*)(gAf + np * 32);
            rAf[s][0] = g[0]; rAf[s][1] = g[1];
            rAf[s][2] = g[2]; rAf[s][3] = g[3];
        } else {
            const ushort8* g = (const ushort8*)(gAh + np * 32);
            rAh[s][0] = g[0]; rAh[s][1] = g[1];
        }
        const floatx4* gb = (const floatx4*)(gB + np * 32);
        rBf[s][0] = gb[0]; rBf[s][1] = gb[1];
        rBf[s][2] = gb[2]; rBf[s][3] = gb[3];
    };
    auto cv8 = [](floatx4 a, floatx4 b) {
        ushort8 o;
#pragma unroll
        for (int j = 0; j < 4; ++j) { o[j] = f2bf(a[j]); o[j + 4] = f2bf(b[j]); }
        return o;
    };
    auto put = [&](int s, int buf) {
        if constexpr (AF32) {
            *(ushort8*)wA[buf]       = cv8(rAf[s][0], rAf[s][1]);
            *(ushort8*)(wA[buf] + 8) = cv8(rAf[s][2], rAf[s][3]);
        } else {
            *(ushort8*)wA[buf]       = rAh[s][0];
            *(ushort8*)(wA[buf] + 8) = rAh[s][1];
        }
        *(ushort8*)wB[buf]       = cv8(rBf[s][0], rBf[s][1]);
        *(ushort8*)(wB[buf] + 8) = cv8(rBf[s][2], rBf[s][3]);
    };
    auto compute = [&](const unsigned short* Ah, const unsigned short* Bh) {
        short8 af[4], bfr[4];
#pragma unroll
        for (int mi = 0; mi < 4; ++mi)
            af[mi] = *(const short8*)
                &Ah[(wm * 64 + mi * 16 + c) * LDT + q * 8];
#pragma unroll
        for (int ni = 0; ni < 4; ++ni)
            bfr[ni] = *(const short8*)
                &Bh[(wn * 64 + ni * 16 + c) * LDT + q * 8];
#pragma unroll
        for (int mi = 0; mi < 4; ++mi)
#pragma unroll
            for (int ni = 0; ni < 4; ++ni)
                acc[mi][ni] = MFMA32(af[mi], bfr[ni], acc[mi][ni]);
    };

    // prologue: tiles 0,1 -> sets 0,1; tile 0 -> buf 0
    load(0, 0);
    load(1, 1);
    put(0, 0);   // compiler waits vmcnt for set-0 loads only
    asm volatile("s_waitcnt lgkmcnt(0)" ::: "memory");

#pragma unroll 2
    for (int p = 0; p < 32; ++p) {
        __builtin_amdgcn_s_barrier();
        __builtin_amdgcn_sched_barrier(0);
        load(p + 2, p & 1);              // set[p&1]'s old tile is in LDS
        compute((p & 1) ? As1 : As0, (p & 1) ? Bs1 : Bs0);
        __builtin_amdgcn_sched_barrier(0);
        put((p + 1) & 1, (p + 1) & 1);   // cvt + write tile p+1
        asm volatile("s_waitcnt lgkmcnt(0)" ::: "memory");
    }

#pragma unroll
    for (int ni = 0; ni < 4; ++ni) {
        const int col = n0 + wn * 64 + ni * 16 + c;
        const float bv = bias[col];
#pragma unroll
        for (int mi = 0; mi < 4; ++mi)
#pragma unroll
            for (int r = 0; r < 4; ++r) {
                const int row = m0 + wm * 64 + mi * 16 + q * 4 + r;
                const float v = (acc[mi][ni][r] + bv) * oscale;
                if constexpr (OMODE == 0) {
                    ((unsigned short*)Cv)[(size_t)row * N + col] = f2bf(v);
                } else if constexpr (OMODE == 1) {
                    const int b = row >> 11, s = row & 2047;
                    ((unsigned short*)Cv)[((size_t)(b * 1024 + col)) * SS + s] = f2bf(v);
                } else {
                    ((float*)Cv)[(size_t)row * N + col] = v;
                }
            }
    }
}

// grid (24 n-tiles, 32 m-tiles): same-W-tile blocks share an XCD (24 % 8 == 0).
// Reads x,y,W as fp32 directly (L3-resident); converts during staging.
__global__ __launch_bounds__(256) void k_gemm_qkv(
    const float* __restrict__ x, const float* __restrict__ y,
    const float* __restrict__ Wq, const float* __restrict__ bq,
    const float* __restrict__ Wk, const float* __restrict__ bk,
    const float* __restrict__ Wv, const float* __restrict__ bv,
    unsigned short* __restrict__ Q, unsigned short* __restrict__ Ko,
    unsigned short* __restrict__ Vt)
{
    __shared__ __align__(16) unsigned short As0[128 * 32], As1[128 * 32];
    __shared__ __align__(16) unsigned short Bs0[128 * 32], Bs1[128 * 32];
    const int m0 = blockIdx.y * 128;
    const int nt = blockIdx.x;
    const int g = nt >> 3;
    const int n0 = (nt & 7) * 128;
    if (g == 0) {
        gemm_fused<0, true>(x, Wq, bq, Q, QSCALE, m0, n0, As0, As1, Bs0, Bs1);
    } else if (g == 1) {
        gemm_fused<0, true>(y, Wk, bk, Ko, 1.0f, m0, n0, As0, As1, Bs0, Bs1);
    } else {
        gemm_fused<1, true>(y, Wv, bv, Vt, 1.0f, m0, n0, As0, As1, Bs0, Bs1);
    }
}

// grid (8 n-tiles, 32 m-tiles): A = attn output (bf16 passthrough), W = Wo fp32.
__global__ __launch_bounds__(256) void k_gemm_out(
    const unsigned short* __restrict__ A, const float* __restrict__ W,
    const float* __restrict__ bias, float* __restrict__ C)
{
    __shared__ __align__(16) unsigned short As0[128 * 32], As1[128 * 32];
    __shared__ __align__(16) unsigned short Bs0[128 * 32], Bs1[128 * 32];
    gemm_fused<2, false>(A, W, bias, C, 1.0f, blockIdx.y * 128,
                         blockIdx.x * 128, As0, As1, Bs0, Bs1);
}

// ---------------------------------------------------------------------------
// Flash attention v8 (unchanged from R7; at its structural floor ~52us after
// three scheduling variants all landed flat -- see R6/R7 notes).
// 8 waves, split-K halves, dbuf LDS + 2-deep reg prefetch, raw barriers +
// lgkmcnt only, additive combine (no running max; pre-scaled exp2 direct).
// ---------------------------------------------------------------------------
__global__ __launch_bounds__(512, 4) void k_attn(
    const unsigned short* __restrict__ Q, const unsigned short* __restrict__ K,
    const unsigned short* __restrict__ Vt, unsigned short* __restrict__ O)
{
    constexpr int LDK = 72;             // b128 frag reads: depth-8 uniform
    constexpr int TSZ = 64 * LDK + 64 * 64;  // ushorts per K+V buffer
    __shared__ __align__(16) unsigned short smem[2 * 2 * TSZ];  // 69632 B
    float* Ob = (float*)smem;           // combine reuse: [128][66] fp32

    const int bh = blockIdx.x, qt = blockIdx.y;
    const int b = bh >> 4, h = bh & 15;
    const int t = threadIdx.x, w = t >> 6;
    const int ws = w >> 2;   // key half: 0 -> keys [0,1024), 1 -> [1024,2048)
    const int wq = w & 3;    // Q-row group within the 128-row tile
    const int lane = t & 63, q = lane >> 4, c = lane & 15;

    unsigned short* Sb = smem + ws * (2 * TSZ);  // this half's buffer pair

    // Q B-frags (B[k=d=q*8+j][n=qrow=c]), two 16-row groups per wave.
    short8 qb[2][2];
#pragma unroll
    for (int g = 0; g < 2; ++g) {
        const size_t qoff =
            (size_t)(b * SS + qt * 128 + wq * 32 + g * 16 + c) * EE + h * DD + q * 8;
        qb[g][0] = *(const short8*)(Q + qoff);
        qb[g][1] = *(const short8*)(Q + qoff + 32);
    }

    floatx4 o[2][4] = {};
    floatx4 lacc[2] = {};
    const shortx4 ones = {(short)0x3F80, (short)0x3F80, (short)0x3F80, (short)0x3F80};

    // staging: each 256-thread half stages its own K/V tile (64 keys x 64 d).
    const int ts = t & 255;
    const int sr = ts >> 2, sp = (ts & 3) * 16;  // staging row / col chunk
    const int vkey = (sr & 15) << 2;
    const unsigned short* Kg =
        K + (size_t)(b * SS + ws * 1024 + sr) * EE + h * DD + sp;
    const unsigned short* Vg =
        Vt + ((size_t)bh * DD + sr) * SS + ws * 1024 + sp;

    // write one staged tile (regs -> LDS buffer)
    auto put = [&](unsigned short* Ks, unsigned short* Vs,
                   ushort8 k0, ushort8 k1, ushort8 v0, ushort8 v1) {
        *(ushort8*)&Ks[sr * LDK + sp] = k0;
        *(ushort8*)&Ks[sr * LDK + sp + 8] = k1;
        *(ush4*)&Vs[sr * 64 + ((sp +  0) ^ vkey)] =
            __builtin_shufflevector(v0, v0, 0, 1, 2, 3);
        *(ush4*)&Vs[sr * 64 + ((sp +  4) ^ vkey)] =
            __builtin_shufflevector(v0, v0, 4, 5, 6, 7);
        *(ush4*)&Vs[sr * 64 + ((sp +  8) ^ vkey)] =
            __builtin_shufflevector(v1, v1, 0, 1, 2, 3);
        *(ush4*)&Vs[sr * 64 + ((sp + 12) ^ vkey)] =
            __builtin_shufflevector(v1, v1, 4, 5, 6, 7);
    };

    // prologue: load tiles 0,1 -> reg sets 0,1; write tile 0 -> buf 0.
    ushort8 rk[2][2], rv[2][2];
    {
        const ushort8* gk0 = (const ushort8*)Kg;
        rk[0][0] = gk0[0]; rk[0][1] = gk0[1];
        const ushort8* gv0 = (const ushort8*)Vg;
        rv[0][0] = gv0[0]; rv[0][1] = gv0[1];
        const ushort8* gk1 = (const ushort8*)(Kg + (size_t)64 * EE);
        rk[1][0] = gk1[0]; rk[1][1] = gk1[1];
        const ushort8* gv1 = (const ushort8*)(Vg + 64);
        rv[1][0] = gv1[0]; rv[1][1] = gv1[1];
        put(Sb, Sb + 64 * LDK, rk[0][0], rk[0][1], rv[0][0], rv[0][1]);
        asm volatile("s_waitcnt lgkmcnt(0)" ::: "memory");
    }

#pragma unroll 2
    for (int it = 0; it < 16; ++it) {
        const unsigned short* Ks = Sb + (it & 1) * TSZ;
        const unsigned short* Vs = Ks + 64 * LDK;
        __builtin_amdgcn_s_barrier();   // buf[it&1] visible; prev reads done
        __builtin_amdgcn_sched_barrier(0);

        // issue loads tile it+2 -> set[it&1] (its old content, tile it, was
        // written to LDS at iter it-1). Wrap at tail -> dead reg loads only.
        {
            const int nit = (it + 2) & 15;
            const ushort8* gk = (const ushort8*)(Kg + (size_t)nit * 64 * EE);
            rk[it & 1][0] = gk[0]; rk[it & 1][1] = gk[1];
            const ushort8* gv = (const ushort8*)(Vg + nit * 64);
            rv[it & 1][0] = gv[0]; rv[it & 1][1] = gv[1];
        }

        // Fused per-K-slice: S^T (A = K rows sk=tt*16+c, B = Q rows) -> exp2
        // -> pack -> PV + lsum. Lane: P[sk=tt*16+q*4+r][qrow=c].
#pragma unroll
        for (int tt = 0; tt < 4; ++tt) {
            const short8 ka0 = *(const short8*)&Ks[(tt * 16 + c) * LDK + q * 8];
            const short8 ka1 = *(const short8*)&Ks[(tt * 16 + c) * LDK + 32 + q * 8];
            shortx4 pa[2];
#pragma unroll
            for (int g = 0; g < 2; ++g) {
                floatx4 s = {0.f, 0.f, 0.f, 0.f};
                s = MFMA32(ka0, qb[g][0], s);
                s = MFMA32(ka1, qb[g][1], s);
                union { unsigned int u[2]; shortx4 v; } pk;
                pk.u[0] = pkbf(__builtin_amdgcn_exp2f(s[0]),
                               __builtin_amdgcn_exp2f(s[1]));
                pk.u[1] = pkbf(__builtin_amdgcn_exp2f(s[2]),
                               __builtin_amdgcn_exp2f(s[3]));
                pa[g] = pk.v;
            }
            // O += P*V: A[m=qrow=c][k=q*4+j]; B[k][n=dv=c] from swizzled Vs.
#pragma unroll
            for (int nd = 0; nd < 4; ++nd) {
                const shortx4 vb = *(const shortx4*)
                    &Vs[(nd * 16 + c) * 64 + (((tt * 4 + q) ^ c) << 2)];
                o[0][nd] = MFMA16(pa[0], vb, o[0][nd]);
                o[1][nd] = MFMA16(pa[1], vb, o[1][nd]);
            }
            lacc[0] = MFMA16(pa[0], ones, lacc[0]);
            lacc[1] = MFMA16(pa[1], ones, lacc[1]);
        }

        __builtin_amdgcn_sched_barrier(0);  // keep writes (and their vmcnt
                                            // wait) below the compute
        // write tile it+1 (set[(it+1)&1]) -> buf[(it+1)&1]; compiler emits
        // counted vmcnt here -- tile it+2's loads stay in flight
        {
            unsigned short* Kn = Sb + ((it + 1) & 1) * TSZ;
            unsigned short* Vn = Kn + 64 * LDK;
            put(Kn, Vn, rk[(it + 1) & 1][0], rk[(it + 1) & 1][1],
                rv[(it + 1) & 1][0], rv[(it + 1) & 1][1]);
        }
        asm volatile("s_waitcnt lgkmcnt(0)" ::: "memory");
    }

    // ---- combine the two key halves (additive: no running max) ----
    __syncthreads();  // full drain; safe to reuse smem as Ob
    if (ws == 1) {
#pragma unroll
        for (int g = 0; g < 2; ++g) {
#pragma unroll
            for (int nd = 0; nd < 4; ++nd)
#pragma unroll
                for (int r = 0; r < 4; ++r)
                    Ob[(wq * 32 + g * 16 + q * 4 + r) * 66 + nd * 16 + c] =
                        o[g][nd][r];
            if (c == 0) {
#pragma unroll
                for (int r = 0; r < 4; ++r)
                    Ob[(wq * 32 + g * 16 + q * 4 + r) * 66 + 64] = lacc[g][r];
            }
        }
    }
    __syncthreads();
    if (ws == 0) {
#pragma unroll
        for (int g = 0; g < 2; ++g) {
            float linv[4];
#pragma unroll
            for (int r = 0; r < 4; ++r) {
                const int rr = wq * 32 + g * 16 + q * 4 + r;
#pragma unroll
                for (int nd = 0; nd < 4; ++nd)
                    o[g][nd][r] += Ob[rr * 66 + nd * 16 + c];
                linv[r] = __builtin_amdgcn_rcpf(lacc[g][r] + Ob[rr * 66 + 64]);
            }
            const int orow = b * SS + qt * 128 + wq * 32 + g * 16;
#pragma unroll
            for (int nd = 0; nd < 4; ++nd)
#pragma unroll
                for (int r = 0; r < 4; ++r)
                    O[(size_t)(orow + q * 4 + r) * EE + h * DD + nd * 16 + c] =
                        f2bf(o[g][nd][r] * linv[r]);
        }
    }
}

// ---------------------------------------------------------------------------
extern "C" void kernel_launch(void* const* d_in, const int* in_sizes, int n_in,
                              void* d_out, int out_size, void* d_ws, size_t ws_size,
                              hipStream_t stream)
{
    const float* x  = (const float*)d_in[0];
    const float* y  = (const float*)d_in[1];
    // d_in[2] = mask (int32) — faithfully ignored, as in the reference
    const float* Wq = (const float*)d_in[3];
    const float* bq = (const float*)d_in[4];
    const float* Wk = (const float*)d_in[5];
    const float* bk = (const float*)d_in[6];
    const float* Wv = (const float*)d_in[7];
    const float* bv = (const float*)d_in[8];
    const float* Wo = (const float*)d_in[9];
    const float* bo = (const float*)d_in[10];
    float* out = (float*)d_out;

    char* ws = (char*)d_ws;
    const size_t SZ = (size_t)BB * SS * EE * sizeof(unsigned short);  // 8 MiB
    unsigned short* Qw  = (unsigned short*)(ws);
    unsigned short* Kw  = (unsigned short*)(ws + SZ);
    unsigned short* Vtw = (unsigned short*)(ws + 2 * SZ);
    unsigned short* Aw  = (unsigned short*)(ws + 3 * SZ);
    (void)ws_size; (void)in_sizes; (void)n_in; (void)out_size;

    k_gemm_qkv<<<dim3(24, 32), 256, 0, stream>>>(x, y, Wq, bq, Wk, bk, Wv, bv,
                                                 Qw, Kw, Vtw);
    k_attn<<<dim3(32, 16), 512, 0, stream>>>(Qw, Kw, Vtw, Aw);
    k_gemm_out<<<dim3(8, 32), 256, 0, stream>>>(Aw, Wo, bo, out);
}

// Round 9
// 229.161 us; speedup vs baseline: 1.0798x; 1.0798x over previous
//
#include <hip/hip_runtime.h>
#include <cstdint>
#include <cstddef>

// Problem constants
#define BB 2
#define SS 2048
#define EE 1024
#define HH 16
#define DD 64

typedef __attribute__((ext_vector_type(8))) short short8;           // 16x16x32 A/B frag
typedef __attribute__((ext_vector_type(4))) short shortx4;          // 16x16x16 A/B frag
typedef __attribute__((ext_vector_type(8))) unsigned short ushort8; // 16B vector ld/st
typedef __attribute__((ext_vector_type(4))) unsigned short ush4;    // 8B vector st
typedef __attribute__((ext_vector_type(4))) float floatx4;          // MFMA C/D frag / float4

#define MFMA32(a, b, c) __builtin_amdgcn_mfma_f32_16x16x32_bf16((a), (b), (c), 0, 0, 0)
#define MFMA16(a, b, c) __builtin_amdgcn_mfma_f32_16x16x16bf16_1k((a), (b), (c), 0, 0, 0)

// 0.125 (1/sqrt(64)) * log2(e): folded into Q so attn can use exp2 directly.
#define QSCALE 0.18033688011112042f

// direct global->LDS async copy, 16B/lane; LDS dest = wave-uniform base + lane*16
#define G2L16(g, l)                                                        \
    __builtin_amdgcn_global_load_lds(                                      \
        (const __attribute__((address_space(1))) void*)(g),                \
        (__attribute__((address_space(3))) void*)(l), 16, 0, 0)

// float -> bf16 bits, round-to-nearest-even
__device__ __forceinline__ unsigned short f2bf(float f) {
    unsigned int u = __float_as_uint(f);
    u += 0x7fffu + ((u >> 16) & 1u);
    return (unsigned short)(u >> 16);
}

// pack two floats into bf16x2 (round-half-up): 2 adds + 1 v_perm
__device__ __forceinline__ unsigned int pkbf(float a, float b) {
    return __builtin_amdgcn_perm(__float_as_uint(b) + 0x8000u,
                                 __float_as_uint(a) + 0x8000u, 0x07060302u);
}

// ---------------------------------------------------------------------------
// fp32 -> bf16 bulk converter, all 6 tensors in one launch.
// R9: RESTORED after the R8 fusion regression (fusing fp32 reads into GEMM
// staging doubled per-dispatch HBM fetch 103->196 MB: the fp32 operands'
// ~768 MB logical re-read volume exceeds L3 retention, so cvt-once + compact
// bf16 re-reads is strictly cheaper). Grid flattened to exactly 3072 live
// blocks (the old (1024,6) grid launched 3072 dead early-exit blocks for the
// weight slices).  bid<1024 -> x; <2048 -> y; else weight (bid-2048)>>8.
// ---------------------------------------------------------------------------
__global__ __launch_bounds__(256) void k_cvt(
    const float* __restrict__ x, unsigned short* __restrict__ xb,
    const float* __restrict__ y, unsigned short* __restrict__ yb,
    const float* __restrict__ w0, unsigned short* __restrict__ d0,
    const float* __restrict__ w1, unsigned short* __restrict__ d1,
    const float* __restrict__ w2, unsigned short* __restrict__ d2,
    const float* __restrict__ w3, unsigned short* __restrict__ d3)
{
    const int bid = blockIdx.x;
    const float* s;
    unsigned short* d;
    int off;
    if (bid < 1024)      { s = x; d = xb; off = bid; }
    else if (bid < 2048) { s = y; d = yb; off = bid - 1024; }
    else {
        const int g = (bid - 2048) >> 8;
        off = (bid - 2048) & 255;
        s = (g == 0) ? w0 : (g == 1) ? w1 : (g == 2) ? w2 : w3;
        d = (g == 0) ? d0 : (g == 1) ? d1 : (g == 2) ? d2 : d3;
    }
    const size_t i = ((size_t)off * 256 + threadIdx.x) * 16;
    floatx4 f0 = *(const floatx4*)(s + i);
    floatx4 f1 = *(const floatx4*)(s + i + 4);
    floatx4 f2 = *(const floatx4*)(s + i + 8);
    floatx4 f3 = *(const floatx4*)(s + i + 12);
    ushort8 o0, o1;
#pragma unroll
    for (int j = 0; j < 4; ++j) { o0[j] = f2bf(f0[j]); o0[j + 4] = f2bf(f1[j]); }
#pragma unroll
    for (int j = 0; j < 4; ++j) { o1[j] = f2bf(f2[j]); o1[j + 4] = f2bf(f3[j]); }
    *(ushort8*)(d + i) = o0;
    *(ushort8*)(d + i + 8) = o1;
}

// ---------------------------------------------------------------------------
// GEMM: C[M,N] = (A[M,K] * W[N,K]^T + bias[N]) * oscale, bf16 in, fp32 accum.
// v4 (R6, best measured): 2-deep prefetch, 3 LDS buffers, counted vmcnt.
// Phase p: { s_barrier; stage(p+2 -> buf[(p+2)%3]); s_waitcnt vmcnt(KEEP)
// (waits loads(p) only; p+1, p+2 stay in flight); s_barrier; compute(p%3) }.
// WAR: stage(p+2) writes the buffer computed at p-1, separated by the phase-p
// barrier. RAW: vmcnt(KEEP) + barrier => tile-p LDS writes visible. Dead
// wrap-stages keep loads unconditional; final vmcnt(0) drains them before
// the epilogue (their LDS dest is reallocated at wave exit).
// OMODE: 0 = bf16 row-major [M][1024], 1 = bf16 V-transposed [b*1024+col][2048],
//        2 = fp32 row-major [M][1024].
// ---------------------------------------------------------------------------
template <int MT, int OMODE>
__device__ __forceinline__ void gemm_body(
    const unsigned short* __restrict__ A, const unsigned short* __restrict__ W,
    const float* __restrict__ bias, void* __restrict__ Cv, float oscale,
    int m0, int n0,
    unsigned short* As0, unsigned short* As1, unsigned short* As2,
    unsigned short* Bs0, unsigned short* Bs1, unsigned short* Bs2)
{
    constexpr int K = 1024, N = 1024, LDT = 32;
    constexpr int MFR = MT / 32;  // m-frags per wave (wave tile = MT/2 x 64)
    constexpr int KEEP = (MT == 128) ? 8 : 6;  // 2 stages (2*loads) in flight
    const int t = threadIdx.x;
    const int lane = t & 63, w = t >> 6;
    const int q = lane >> 4, c = lane & 15;
    const int wm = w & 1, wn = w >> 1;
    const int lr = lane >> 2, lc = (lane & 3) * 8;  // 16 rows x 64B per G2L16

    // A staging: wave w covers rows w*(MT/4) .. +(MT/4)-1, in 16-row instrs.
    const unsigned short* gA0 = A + (size_t)(m0 + w * (MT / 4) + lr) * K + lc;
    const unsigned short* gA1 = gA0 + 16 * K;  // MT==128 only
    const unsigned short* gB0 = W + (size_t)(n0 + w * 32 + lr) * K + lc;
    const unsigned short* gB1 = gB0 + 16 * K;
    unsigned short* lA0 = As0 + (w * (MT / 4)) * LDT;
    unsigned short* lA1 = As1 + (w * (MT / 4)) * LDT;
    unsigned short* lA2 = As2 + (w * (MT / 4)) * LDT;
    unsigned short* lB0 = Bs0 + (w * 32) * LDT;
    unsigned short* lB1 = Bs1 + (w * 32) * LDT;
    unsigned short* lB2 = Bs2 + (w * 32) * LDT;

    floatx4 acc[MFR][4] = {};

    // compute one 32-K subtile from buffer (Ah,Bh)
    auto compute = [&](const unsigned short* Ah, const unsigned short* Bh) {
        short8 af[MFR], bfr[4];
#pragma unroll
        for (int mi = 0; mi < MFR; ++mi)
            af[mi] = *(const short8*)
                &Ah[(wm * (MFR * 16) + mi * 16 + c) * LDT + q * 8];
#pragma unroll
        for (int ni = 0; ni < 4; ++ni)
            bfr[ni] = *(const short8*)
                &Bh[(wn * 64 + ni * 16 + c) * LDT + q * 8];
#pragma unroll
        for (int mi = 0; mi < MFR; ++mi)
#pragma unroll
            for (int ni = 0; ni < 4; ++ni)
                acc[mi][ni] = MFMA32(af[mi], bfr[ni], acc[mi][ni]);
    };

    // stage one 32-K subtile (KEEP/2 G2L16 instructions)
    auto stage = [&](int nk, unsigned short* lA, unsigned short* lB) {
        G2L16(gA0 + nk, lA);
        if constexpr (MT == 128) G2L16(gA1 + nk, lA + 16 * LDT);
        G2L16(gB0 + nk, lB);
        G2L16(gB1 + nk, lB + 16 * LDT);
    };

    // one phase: stage subtile (knext -> lAn/lBn), compute buffer (Ac,Bc)
    auto phase = [&](int knext, unsigned short* lAn, unsigned short* lBn,
                     const unsigned short* Ac, const unsigned short* Bc) {
        __builtin_amdgcn_s_barrier();            // WAR: prev compute done
        stage(knext & (K - 1), lAn, lBn);        // wrap -> dead re-stage
        asm volatile("s_waitcnt vmcnt(%0)" :: "n"(KEEP) : "memory");
        __builtin_amdgcn_s_barrier();            // RAW: current buf visible
        __builtin_amdgcn_sched_barrier(0);
        compute(Ac, Bc);
    };

    // prologue: subtiles 0,1 -> buffers 0,1 (8 loads in flight)
    stage(0, lA0, lB0);
    stage(32, lA1, lB1);

    // phases p = 0..31 (subtile p in buffer p%3, stage p+2 into (p+2)%3)
    for (int g = 0; g < 10; ++g) {
        const int kb = g * 96;
        phase(kb +  64, lA2, lB2, As0, Bs0);  // p=3g
        phase(kb +  96, lA0, lB0, As1, Bs1);  // p=3g+1
        phase(kb + 128, lA1, lB1, As2, Bs2);  // p=3g+2 (g=9: dead-stage 0)
    }
    phase(1056, lA2, lB2, As0, Bs0);          // p=30: k=960, dead-stage
    phase(1088, lA0, lB0, As1, Bs1);          // p=31: k=992, dead-stage
    // drain dead prefetches: they must not be outstanding at s_endpgm (their
    // LDS destination is reallocated to the next block on this CU).
    asm volatile("s_waitcnt vmcnt(0)" ::: "memory");

#pragma unroll
    for (int ni = 0; ni < 4; ++ni) {
        const int col = n0 + wn * 64 + ni * 16 + c;
        const float bv = bias[col];
#pragma unroll
        for (int mi = 0; mi < MFR; ++mi)
#pragma unroll
            for (int r = 0; r < 4; ++r) {
                const int row = m0 + wm * (MFR * 16) + mi * 16 + q * 4 + r;
                const float v = (acc[mi][ni][r] + bv) * oscale;
                if constexpr (OMODE == 0) {
                    ((unsigned short*)Cv)[(size_t)row * N + col] = f2bf(v);
                } else if constexpr (OMODE == 1) {
                    const int b = row >> 11, s = row & 2047;
                    ((unsigned short*)Cv)[((size_t)(b * 1024 + col)) * SS + s] = f2bf(v);
                } else {
                    ((float*)Cv)[(size_t)row * N + col] = v;
                }
            }
    }
}

// grid (24 n-tiles, 32 m-tiles): same-W-tile blocks share an XCD (24 % 8 == 0).
__global__ __launch_bounds__(256) void k_gemm_qkv(
    const unsigned short* __restrict__ x, const unsigned short* __restrict__ y,
    const unsigned short* __restrict__ Wq, const float* __restrict__ bq,
    const unsigned short* __restrict__ Wk, const float* __restrict__ bk,
    const unsigned short* __restrict__ Wv, const float* __restrict__ bv,
    unsigned short* __restrict__ Q, unsigned short* __restrict__ Ko,
    unsigned short* __restrict__ Vt)
{
    __shared__ __align__(16) unsigned short As0[128 * 32], As1[128 * 32],
                                            As2[128 * 32];
    __shared__ __align__(16) unsigned short Bs0[128 * 32], Bs1[128 * 32],
                                            Bs2[128 * 32];
    const int m0 = blockIdx.y * 128;
    const int nt = blockIdx.x;
    const int g = nt >> 3;
    const int n0 = (nt & 7) * 128;
    if (g == 0) {
        gemm_body<128, 0>(x, Wq, bq, Q, QSCALE, m0, n0,
                          As0, As1, As2, Bs0, Bs1, Bs2);
    } else if (g == 1) {
        gemm_body<128, 0>(y, Wk, bk, Ko, 1.0f, m0, n0,
                          As0, As1, As2, Bs0, Bs1, Bs2);
    } else {
        gemm_body<128, 1>(y, Wv, bv, Vt, 1.0f, m0, n0,
                          As0, As1, As2, Bs0, Bs1, Bs2);
    }
}

// grid (8 n-tiles, 64 m-tiles), fp32 output. MT=64 (R6 best; the R7 MT=128
// 1-block/CU variant measured ~4us worse).
__global__ __launch_bounds__(256) void k_gemm_out(
    const unsigned short* __restrict__ A, const unsigned short* __restrict__ W,
    const float* __restrict__ bias, float* __restrict__ C)
{
    __shared__ __align__(16) unsigned short As0[64 * 32], As1[64 * 32],
                                            As2[64 * 32];
    __shared__ __align__(16) unsigned short Bs0[128 * 32], Bs1[128 * 32],
                                            Bs2[128 * 32];
    gemm_body<64, 2>(A, W, bias, C, 1.0f, blockIdx.y * 64, blockIdx.x * 128,
                     As0, As1, As2, Bs0, Bs1, Bs2);
}

// ---------------------------------------------------------------------------
// Flash attention v8 (R7; structural floor ~52us — three scheduling variants
// flat; real matrix-pipe <10%, DS ~29%, nothing saturated => latency floor of
// this structure). 8 waves, split-K halves, dbuf LDS + 2-deep reg prefetch,
// raw barriers + lgkmcnt only, additive combine (pre-scaled exp2, no max).
// ---------------------------------------------------------------------------
__global__ __launch_bounds__(512, 4) void k_attn(
    const unsigned short* __restrict__ Q, const unsigned short* __restrict__ K,
    const unsigned short* __restrict__ Vt, unsigned short* __restrict__ O)
{
    constexpr int LDK = 72;             // b128 frag reads: depth-8 uniform
    constexpr int TSZ = 64 * LDK + 64 * 64;  // ushorts per K+V buffer
    __shared__ __align__(16) unsigned short smem[2 * 2 * TSZ];  // 69632 B
    float* Ob = (float*)smem;           // combine reuse: [128][66] fp32

    const int bh = blockIdx.x, qt = blockIdx.y;
    const int b = bh >> 4, h = bh & 15;
    const int t = threadIdx.x, w = t >> 6;
    const int ws = w >> 2;   // key half: 0 -> keys [0,1024), 1 -> [1024,2048)
    const int wq = w & 3;    // Q-row group within the 128-row tile
    const int lane = t & 63, q = lane >> 4, c = lane & 15;

    unsigned short* Sb = smem + ws * (2 * TSZ);  // this half's buffer pair

    // Q B-frags (B[k=d=q*8+j][n=qrow=c]), two 16-row groups per wave.
    short8 qb[2][2];
#pragma unroll
    for (int g = 0; g < 2; ++g) {
        const size_t qoff =
            (size_t)(b * SS + qt * 128 + wq * 32 + g * 16 + c) * EE + h * DD + q * 8;
        qb[g][0] = *(const short8*)(Q + qoff);
        qb[g][1] = *(const short8*)(Q + qoff + 32);
    }

    floatx4 o[2][4] = {};
    floatx4 lacc[2] = {};
    const shortx4 ones = {(short)0x3F80, (short)0x3F80, (short)0x3F80, (short)0x3F80};

    // staging: each 256-thread half stages its own K/V tile (64 keys x 64 d).
    const int ts = t & 255;
    const int sr = ts >> 2, sp = (ts & 3) * 16;  // staging row / col chunk
    const int vkey = (sr & 15) << 2;
    const unsigned short* Kg =
        K + (size_t)(b * SS + ws * 1024 + sr) * EE + h * DD + sp;
    const unsigned short* Vg =
        Vt + ((size_t)bh * DD + sr) * SS + ws * 1024 + sp;

    // write one staged tile (regs -> LDS buffer)
    auto put = [&](unsigned short* Ks, unsigned short* Vs,
                   ushort8 k0, ushort8 k1, ushort8 v0, ushort8 v1) {
        *(ushort8*)&Ks[sr * LDK + sp] = k0;
        *(ushort8*)&Ks[sr * LDK + sp + 8] = k1;
        *(ush4*)&Vs[sr * 64 + ((sp +  0) ^ vkey)] =
            __builtin_shufflevector(v0, v0, 0, 1, 2, 3);
        *(ush4*)&Vs[sr * 64 + ((sp +  4) ^ vkey)] =
            __builtin_shufflevector(v0, v0, 4, 5, 6, 7);
        *(ush4*)&Vs[sr * 64 + ((sp +  8) ^ vkey)] =
            __builtin_shufflevector(v1, v1, 0, 1, 2, 3);
        *(ush4*)&Vs[sr * 64 + ((sp + 12) ^ vkey)] =
            __builtin_shufflevector(v1, v1, 4, 5, 6, 7);
    };

    // prologue: load tiles 0,1 -> reg sets 0,1; write tile 0 -> buf 0.
    ushort8 rk[2][2], rv[2][2];
    {
        const ushort8* gk0 = (const ushort8*)Kg;
        rk[0][0] = gk0[0]; rk[0][1] = gk0[1];
        const ushort8* gv0 = (const ushort8*)Vg;
        rv[0][0] = gv0[0]; rv[0][1] = gv0[1];
        const ushort8* gk1 = (const ushort8*)(Kg + (size_t)64 * EE);
        rk[1][0] = gk1[0]; rk[1][1] = gk1[1];
        const ushort8* gv1 = (const ushort8*)(Vg + 64);
        rv[1][0] = gv1[0]; rv[1][1] = gv1[1];
        put(Sb, Sb + 64 * LDK, rk[0][0], rk[0][1], rv[0][0], rv[0][1]);
        asm volatile("s_waitcnt lgkmcnt(0)" ::: "memory");
    }

#pragma unroll 2
    for (int it = 0; it < 16; ++it) {
        const unsigned short* Ks = Sb + (it & 1) * TSZ;
        const unsigned short* Vs = Ks + 64 * LDK;
        __builtin_amdgcn_s_barrier();   // buf[it&1] visible; prev reads done
        __builtin_amdgcn_sched_barrier(0);

        // issue loads tile it+2 -> set[it&1] (its old content, tile it, was
        // written to LDS at iter it-1). Wrap at tail -> dead reg loads only.
        {
            const int nit = (it + 2) & 15;
            const ushort8* gk = (const ushort8*)(Kg + (size_t)nit * 64 * EE);
            rk[it & 1][0] = gk[0]; rk[it & 1][1] = gk[1];
            const ushort8* gv = (const ushort8*)(Vg + nit * 64);
            rv[it & 1][0] = gv[0]; rv[it & 1][1] = gv[1];
        }

        // Fused per-K-slice: S^T (A = K rows sk=tt*16+c, B = Q rows) -> exp2
        // -> pack -> PV + lsum. Lane: P[sk=tt*16+q*4+r][qrow=c].
#pragma unroll
        for (int tt = 0; tt < 4; ++tt) {
            const short8 ka0 = *(const short8*)&Ks[(tt * 16 + c) * LDK + q * 8];
            const short8 ka1 = *(const short8*)&Ks[(tt * 16 + c) * LDK + 32 + q * 8];
            shortx4 pa[2];
#pragma unroll
            for (int g = 0; g < 2; ++g) {
                floatx4 s = {0.f, 0.f, 0.f, 0.f};
                s = MFMA32(ka0, qb[g][0], s);
                s = MFMA32(ka1, qb[g][1], s);
                union { unsigned int u[2]; shortx4 v; } pk;
                pk.u[0] = pkbf(__builtin_amdgcn_exp2f(s[0]),
                               __builtin_amdgcn_exp2f(s[1]));
                pk.u[1] = pkbf(__builtin_amdgcn_exp2f(s[2]),
                               __builtin_amdgcn_exp2f(s[3]));
                pa[g] = pk.v;
            }
            // O += P*V: A[m=qrow=c][k=q*4+j]; B[k][n=dv=c] from swizzled Vs.
#pragma unroll
            for (int nd = 0; nd < 4; ++nd) {
                const shortx4 vb = *(const shortx4*)
                    &Vs[(nd * 16 + c) * 64 + (((tt * 4 + q) ^ c) << 2)];
                o[0][nd] = MFMA16(pa[0], vb, o[0][nd]);
                o[1][nd] = MFMA16(pa[1], vb, o[1][nd]);
            }
            lacc[0] = MFMA16(pa[0], ones, lacc[0]);
            lacc[1] = MFMA16(pa[1], ones, lacc[1]);
        }

        __builtin_amdgcn_sched_barrier(0);  // keep writes (and their vmcnt
                                            // wait) below the compute
        // write tile it+1 (set[(it+1)&1]) -> buf[(it+1)&1]; compiler emits
        // counted vmcnt here -- tile it+2's loads stay in flight
        {
            unsigned short* Kn = Sb + ((it + 1) & 1) * TSZ;
            unsigned short* Vn = Kn + 64 * LDK;
            put(Kn, Vn, rk[(it + 1) & 1][0], rk[(it + 1) & 1][1],
                rv[(it + 1) & 1][0], rv[(it + 1) & 1][1]);
        }
        asm volatile("s_waitcnt lgkmcnt(0)" ::: "memory");
    }

    // ---- combine the two key halves (additive: no running max) ----
    __syncthreads();  // full drain; safe to reuse smem as Ob
    if (ws == 1) {
#pragma unroll
        for (int g = 0; g < 2; ++g) {
#pragma unroll
            for (int nd = 0; nd < 4; ++nd)
#pragma unroll
                for (int r = 0; r < 4; ++r)
                    Ob[(wq * 32 + g * 16 + q * 4 + r) * 66 + nd * 16 + c] =
                        o[g][nd][r];
            if (c == 0) {
#pragma unroll
                for (int r = 0; r < 4; ++r)
                    Ob[(wq * 32 + g * 16 + q * 4 + r) * 66 + 64] = lacc[g][r];
            }
        }
    }
    __syncthreads();
    if (ws == 0) {
#pragma unroll
        for (int g = 0; g < 2; ++g) {
            float linv[4];
#pragma unroll
            for (int r = 0; r < 4; ++r) {
                const int rr = wq * 32 + g * 16 + q * 4 + r;
#pragma unroll
                for (int nd = 0; nd < 4; ++nd)
                    o[g][nd][r] += Ob[rr * 66 + nd * 16 + c];
                linv[r] = __builtin_amdgcn_rcpf(lacc[g][r] + Ob[rr * 66 + 64]);
            }
            const int orow = b * SS + qt * 128 + wq * 32 + g * 16;
#pragma unroll
            for (int nd = 0; nd < 4; ++nd)
#pragma unroll
                for (int r = 0; r < 4; ++r)
                    O[(size_t)(orow + q * 4 + r) * EE + h * DD + nd * 16 + c] =
                        f2bf(o[g][nd][r] * linv[r]);
        }
    }
}

// ---------------------------------------------------------------------------
extern "C" void kernel_launch(void* const* d_in, const int* in_sizes, int n_in,
                              void* d_out, int out_size, void* d_ws, size_t ws_size,
                              hipStream_t stream)
{
    const float* x  = (const float*)d_in[0];
    const float* y  = (const float*)d_in[1];
    // d_in[2] = mask (int32) — faithfully ignored, as in the reference
    const float* Wq = (const float*)d_in[3];
    const float* bq = (const float*)d_in[4];
    const float* Wk = (const float*)d_in[5];
    const float* bk = (const float*)d_in[6];
    const float* Wv = (const float*)d_in[7];
    const float* bv = (const float*)d_in[8];
    const float* Wo = (const float*)d_in[9];
    const float* bo = (const float*)d_in[10];
    float* out = (float*)d_out;

    char* ws = (char*)d_ws;
    const size_t SZ = (size_t)BB * SS * EE * sizeof(unsigned short);  // 8 MiB
    const size_t WZ = (size_t)EE * EE * sizeof(unsigned short);       // 2 MiB
    unsigned short* xb  = (unsigned short*)(ws);
    unsigned short* yb  = (unsigned short*)(ws + SZ);
    unsigned short* Wqb = (unsigned short*)(ws + 2 * SZ);
    unsigned short* Wkb = (unsigned short*)(ws + 2 * SZ + WZ);
    unsigned short* Wvb = (unsigned short*)(ws + 2 * SZ + 2 * WZ);
    unsigned short* Wob = (unsigned short*)(ws + 2 * SZ + 3 * WZ);
    unsigned short* Qw  = (unsigned short*)(ws + 2 * SZ + 4 * WZ);
    unsigned short* Kw  = (unsigned short*)(ws + 3 * SZ + 4 * WZ);
    unsigned short* Vtw = (unsigned short*)(ws + 4 * SZ + 4 * WZ);
    unsigned short* Aw  = (unsigned short*)(ws + 5 * SZ + 4 * WZ);
    (void)ws_size; (void)in_sizes; (void)n_in; (void)out_size;

    k_cvt<<<dim3(3072), 256, 0, stream>>>(x, xb, y, yb, Wq, Wqb, Wk, Wkb,
                                          Wv, Wvb, Wo, Wob);
    k_gemm_qkv<<<dim3(24, 32), 256, 0, stream>>>(xb, yb, Wqb, bq, Wkb, bk, Wvb, bv,
                                                 Qw, Kw, Vtw);
    k_attn<<<dim3(32, 16), 512, 0, stream>>>(Qw, Kw, Vtw, Aw);
    k_gemm_out<<<dim3(8, 64), 256, 0, stream>>>(Aw, Wob, bo, out);
}

// Round 11
// 222.991 us; speedup vs baseline: 1.1097x; 1.0277x over previous
//
#include <hip/hip_runtime.h>
#include <cstdint>
#include <cstddef>

// Problem constants
#define BB 2
#define SS 2048
#define EE 1024
#define HH 16
#define DD 64

typedef __attribute__((ext_vector_type(8))) short short8;           // 16x16x32 A/B frag
typedef __attribute__((ext_vector_type(4))) short shortx4;          // 16x16x16 A/B frag
typedef __attribute__((ext_vector_type(8))) unsigned short ushort8; // 16B vector ld/st
typedef __attribute__((ext_vector_type(4))) unsigned short ush4;    // 8B vector st
typedef __attribute__((ext_vector_type(4))) float floatx4;          // MFMA C/D frag / float4

#define MFMA32(a, b, c) __builtin_amdgcn_mfma_f32_16x16x32_bf16((a), (b), (c), 0, 0, 0)
#define MFMA16(a, b, c) __builtin_amdgcn_mfma_f32_16x16x16bf16_1k((a), (b), (c), 0, 0, 0)

// 0.125 (1/sqrt(64)) * log2(e): folded into Q so attn can use exp2 directly.
#define QSCALE 0.18033688011112042f

// direct global->LDS async copy, 16B/lane; LDS dest = wave-uniform base + lane*16
#define G2L16(g, l)                                                        \
    __builtin_amdgcn_global_load_lds(                                      \
        (const __attribute__((address_space(1))) void*)(g),                \
        (__attribute__((address_space(3))) void*)(l), 16, 0, 0)

// float -> bf16 bits, round-to-nearest-even
__device__ __forceinline__ unsigned short f2bf(float f) {
    unsigned int u = __float_as_uint(f);
    u += 0x7fffu + ((u >> 16) & 1u);
    return (unsigned short)(u >> 16);
}

// pack two floats into bf16x2 (round-half-up): 2 adds + 1 v_perm
__device__ __forceinline__ unsigned int pkbf(float a, float b) {
    return __builtin_amdgcn_perm(__float_as_uint(b) + 0x8000u,
                                 __float_as_uint(a) + 0x8000u, 0x07060302u);
}

// ---------------------------------------------------------------------------
// fp32 -> bf16 bulk converter, all 6 tensors in one launch.
// R10/R11: COALESCING FIX (single-variable round; R10 bench was an infra
// failure, resubmitted unchanged). The old per-thread layout had lane i
// loading 4x float4 at byte offsets i*64+{0,16,32,48} -- 64B lane stride, so
// each load instruction scattered 64 lanes over 64 cache lines (16/64 bytes
// used per line per instr; ~0.5x streaming efficiency). Now lane i handles
// float4 index base+k*256+i: every load is 64 lanes x 16B CONTIGUOUS
// (1 KiB/instr), every store 64 x 8B contiguous. Same grid (3072 live
// blocks), same per-block work, bit-identical f2bf rounding.
// bid<1024 -> x; <2048 -> y; else weight (bid-2048)>>8.
// ---------------------------------------------------------------------------
__global__ __launch_bounds__(256) void k_cvt(
    const float* __restrict__ x, unsigned short* __restrict__ xb,
    const float* __restrict__ y, unsigned short* __restrict__ yb,
    const float* __restrict__ w0, unsigned short* __restrict__ d0,
    const float* __restrict__ w1, unsigned short* __restrict__ d1,
    const float* __restrict__ w2, unsigned short* __restrict__ d2,
    const float* __restrict__ w3, unsigned short* __restrict__ d3)
{
    const int bid = blockIdx.x;
    const float* s;
    unsigned short* d;
    int off;
    if (bid < 1024)      { s = x; d = xb; off = bid; }
    else if (bid < 2048) { s = y; d = yb; off = bid - 1024; }
    else {
        const int g = (bid - 2048) >> 8;
        off = (bid - 2048) & 255;
        s = (g == 0) ? w0 : (g == 1) ? w1 : (g == 2) ? w2 : w3;
        d = (g == 0) ? d0 : (g == 1) ? d1 : (g == 2) ? d2 : d3;
    }
    // block owns float4 indices [off*1024, off*1024+1024); lane-contiguous.
    const floatx4* sf = (const floatx4*)s;
#pragma unroll
    for (int k = 0; k < 4; ++k) {
        const size_t fi = (size_t)off * 1024 + k * 256 + threadIdx.x;
        const floatx4 f = sf[fi];
        ush4 o;
#pragma unroll
        for (int j = 0; j < 4; ++j) o[j] = f2bf(f[j]);
        *(ush4*)(d + fi * 4) = o;
    }
}

// ---------------------------------------------------------------------------
// GEMM: C[M,N] = (A[M,K] * W[N,K]^T + bias[N]) * oscale, bf16 in, fp32 accum.
// v4 (R6, best measured): 2-deep prefetch, 3 LDS buffers, counted vmcnt.
// Phase p: { s_barrier; stage(p+2 -> buf[(p+2)%3]); s_waitcnt vmcnt(KEEP)
// (waits loads(p) only; p+1, p+2 stay in flight); s_barrier; compute(p%3) }.
// WAR: stage(p+2) writes the buffer computed at p-1, separated by the phase-p
// barrier. RAW: vmcnt(KEEP) + barrier => tile-p LDS writes visible. Dead
// wrap-stages keep loads unconditional; final vmcnt(0) drains them before
// the epilogue (their LDS dest is reallocated at wave exit).
// OMODE: 0 = bf16 row-major [M][1024], 1 = bf16 V-transposed [b*1024+col][2048],
//        2 = fp32 row-major [M][1024].
// ---------------------------------------------------------------------------
template <int MT, int OMODE>
__device__ __forceinline__ void gemm_body(
    const unsigned short* __restrict__ A, const unsigned short* __restrict__ W,
    const float* __restrict__ bias, void* __restrict__ Cv, float oscale,
    int m0, int n0,
    unsigned short* As0, unsigned short* As1, unsigned short* As2,
    unsigned short* Bs0, unsigned short* Bs1, unsigned short* Bs2)
{
    constexpr int K = 1024, N = 1024, LDT = 32;
    constexpr int MFR = MT / 32;  // m-frags per wave (wave tile = MT/2 x 64)
    constexpr int KEEP = (MT == 128) ? 8 : 6;  // 2 stages (2*loads) in flight
    const int t = threadIdx.x;
    const int lane = t & 63, w = t >> 6;
    const int q = lane >> 4, c = lane & 15;
    const int wm = w & 1, wn = w >> 1;
    const int lr = lane >> 2, lc = (lane & 3) * 8;  // 16 rows x 64B per G2L16

    // A staging: wave w covers rows w*(MT/4) .. +(MT/4)-1, in 16-row instrs.
    const unsigned short* gA0 = A + (size_t)(m0 + w * (MT / 4) + lr) * K + lc;
    const unsigned short* gA1 = gA0 + 16 * K;  // MT==128 only
    const unsigned short* gB0 = W + (size_t)(n0 + w * 32 + lr) * K + lc;
    const unsigned short* gB1 = gB0 + 16 * K;
    unsigned short* lA0 = As0 + (w * (MT / 4)) * LDT;
    unsigned short* lA1 = As1 + (w * (MT / 4)) * LDT;
    unsigned short* lA2 = As2 + (w * (MT / 4)) * LDT;
    unsigned short* lB0 = Bs0 + (w * 32) * LDT;
    unsigned short* lB1 = Bs1 + (w * 32) * LDT;
    unsigned short* lB2 = Bs2 + (w * 32) * LDT;

    floatx4 acc[MFR][4] = {};

    // compute one 32-K subtile from buffer (Ah,Bh)
    auto compute = [&](const unsigned short* Ah, const unsigned short* Bh) {
        short8 af[MFR], bfr[4];
#pragma unroll
        for (int mi = 0; mi < MFR; ++mi)
            af[mi] = *(const short8*)
                &Ah[(wm * (MFR * 16) + mi * 16 + c) * LDT + q * 8];
#pragma unroll
        for (int ni = 0; ni < 4; ++ni)
            bfr[ni] = *(const short8*)
                &Bh[(wn * 64 + ni * 16 + c) * LDT + q * 8];
#pragma unroll
        for (int mi = 0; mi < MFR; ++mi)
#pragma unroll
            for (int ni = 0; ni < 4; ++ni)
                acc[mi][ni] = MFMA32(af[mi], bfr[ni], acc[mi][ni]);
    };

    // stage one 32-K subtile (KEEP/2 G2L16 instructions)
    auto stage = [&](int nk, unsigned short* lA, unsigned short* lB) {
        G2L16(gA0 + nk, lA);
        if constexpr (MT == 128) G2L16(gA1 + nk, lA + 16 * LDT);
        G2L16(gB0 + nk, lB);
        G2L16(gB1 + nk, lB + 16 * LDT);
    };

    // one phase: stage subtile (knext -> lAn/lBn), compute buffer (Ac,Bc)
    auto phase = [&](int knext, unsigned short* lAn, unsigned short* lBn,
                     const unsigned short* Ac, const unsigned short* Bc) {
        __builtin_amdgcn_s_barrier();            // WAR: prev compute done
        stage(knext & (K - 1), lAn, lBn);        // wrap -> dead re-stage
        asm volatile("s_waitcnt vmcnt(%0)" :: "n"(KEEP) : "memory");
        __builtin_amdgcn_s_barrier();            // RAW: current buf visible
        __builtin_amdgcn_sched_barrier(0);
        compute(Ac, Bc);
    };

    // prologue: subtiles 0,1 -> buffers 0,1 (8 loads in flight)
    stage(0, lA0, lB0);
    stage(32, lA1, lB1);

    // phases p = 0..31 (subtile p in buffer p%3, stage p+2 into (p+2)%3)
    for (int g = 0; g < 10; ++g) {
        const int kb = g * 96;
        phase(kb +  64, lA2, lB2, As0, Bs0);  // p=3g
        phase(kb +  96, lA0, lB0, As1, Bs1);  // p=3g+1
        phase(kb + 128, lA1, lB1, As2, Bs2);  // p=3g+2 (g=9: dead-stage 0)
    }
    phase(1056, lA2, lB2, As0, Bs0);          // p=30: k=960, dead-stage
    phase(1088, lA0, lB0, As1, Bs1);          // p=31: k=992, dead-stage
    // drain dead prefetches: they must not be outstanding at s_endpgm (their
    // LDS destination is reallocated to the next block on this CU).
    asm volatile("s_waitcnt vmcnt(0)" ::: "memory");

#pragma unroll
    for (int ni = 0; ni < 4; ++ni) {
        const int col = n0 + wn * 64 + ni * 16 + c;
        const float bv = bias[col];
#pragma unroll
        for (int mi = 0; mi < MFR; ++mi)
#pragma unroll
            for (int r = 0; r < 4; ++r) {
                const int row = m0 + wm * (MFR * 16) + mi * 16 + q * 4 + r;
                const float v = (acc[mi][ni][r] + bv) * oscale;
                if constexpr (OMODE == 0) {
                    ((unsigned short*)Cv)[(size_t)row * N + col] = f2bf(v);
                } else if constexpr (OMODE == 1) {
                    const int b = row >> 11, s = row & 2047;
                    ((unsigned short*)Cv)[((size_t)(b * 1024 + col)) * SS + s] = f2bf(v);
                } else {
                    ((float*)Cv)[(size_t)row * N + col] = v;
                }
            }
    }
}

// grid (24 n-tiles, 32 m-tiles): same-W-tile blocks share an XCD (24 % 8 == 0).
__global__ __launch_bounds__(256) void k_gemm_qkv(
    const unsigned short* __restrict__ x, const unsigned short* __restrict__ y,
    const unsigned short* __restrict__ Wq, const float* __restrict__ bq,
    const unsigned short* __restrict__ Wk, const float* __restrict__ bk,
    const unsigned short* __restrict__ Wv, const float* __restrict__ bv,
    unsigned short* __restrict__ Q, unsigned short* __restrict__ Ko,
    unsigned short* __restrict__ Vt)
{
    __shared__ __align__(16) unsigned short As0[128 * 32], As1[128 * 32],
                                            As2[128 * 32];
    __shared__ __align__(16) unsigned short Bs0[128 * 32], Bs1[128 * 32],
                                            Bs2[128 * 32];
    const int m0 = blockIdx.y * 128;
    const int nt = blockIdx.x;
    const int g = nt >> 3;
    const int n0 = (nt & 7) * 128;
    if (g == 0) {
        gemm_body<128, 0>(x, Wq, bq, Q, QSCALE, m0, n0,
                          As0, As1, As2, Bs0, Bs1, Bs2);
    } else if (g == 1) {
        gemm_body<128, 0>(y, Wk, bk, Ko, 1.0f, m0, n0,
                          As0, As1, As2, Bs0, Bs1, Bs2);
    } else {
        gemm_body<128, 1>(y, Wv, bv, Vt, 1.0f, m0, n0,
                          As0, As1, As2, Bs0, Bs1, Bs2);
    }
}

// grid (8 n-tiles, 64 m-tiles), fp32 output. MT=64 (R6 best; the R7 MT=128
// 1-block/CU variant measured ~4us worse).
__global__ __launch_bounds__(256) void k_gemm_out(
    const unsigned short* __restrict__ A, const unsigned short* __restrict__ W,
    const float* __restrict__ bias, float* __restrict__ C)
{
    __shared__ __align__(16) unsigned short As0[64 * 32], As1[64 * 32],
                                            As2[64 * 32];
    __shared__ __align__(16) unsigned short Bs0[128 * 32], Bs1[128 * 32],
                                            Bs2[128 * 32];
    gemm_body<64, 2>(A, W, bias, C, 1.0f, blockIdx.y * 64, blockIdx.x * 128,
                     As0, As1, As2, Bs0, Bs1, Bs2);
}

// ---------------------------------------------------------------------------
// Flash attention v8 (R7; structural floor ~52us — three scheduling variants
// flat; real matrix-pipe <10%, DS ~49%, nothing saturated => latency floor of
// this structure). 8 waves, split-K halves, dbuf LDS + 2-deep reg prefetch,
// raw barriers + lgkmcnt only, additive combine (pre-scaled exp2, no max).
// UNCHANGED for clean cvt-only attribution.
// ---------------------------------------------------------------------------
__global__ __launch_bounds__(512, 4) void k_attn(
    const unsigned short* __restrict__ Q, const unsigned short* __restrict__ K,
    const unsigned short* __restrict__ Vt, unsigned short* __restrict__ O)
{
    constexpr int LDK = 72;             // b128 frag reads: depth-8 uniform
    constexpr int TSZ = 64 * LDK + 64 * 64;  // ushorts per K+V buffer
    __shared__ __align__(16) unsigned short smem[2 * 2 * TSZ];  // 69632 B
    float* Ob = (float*)smem;           // combine reuse: [128][66] fp32

    const int bh = blockIdx.x, qt = blockIdx.y;
    const int b = bh >> 4, h = bh & 15;
    const int t = threadIdx.x, w = t >> 6;
    const int ws = w >> 2;   // key half: 0 -> keys [0,1024), 1 -> [1024,2048)
    const int wq = w & 3;    // Q-row group within the 128-row tile
    const int lane = t & 63, q = lane >> 4, c = lane & 15;

    unsigned short* Sb = smem + ws * (2 * TSZ);  // this half's buffer pair

    // Q B-frags (B[k=d=q*8+j][n=qrow=c]), two 16-row groups per wave.
    short8 qb[2][2];
#pragma unroll
    for (int g = 0; g < 2; ++g) {
        const size_t qoff =
            (size_t)(b * SS + qt * 128 + wq * 32 + g * 16 + c) * EE + h * DD + q * 8;
        qb[g][0] = *(const short8*)(Q + qoff);
        qb[g][1] = *(const short8*)(Q + qoff + 32);
    }

    floatx4 o[2][4] = {};
    floatx4 lacc[2] = {};
    const shortx4 ones = {(short)0x3F80, (short)0x3F80, (short)0x3F80, (short)0x3F80};

    // staging: each 256-thread half stages its own K/V tile (64 keys x 64 d).
    const int ts = t & 255;
    const int sr = ts >> 2, sp = (ts & 3) * 16;  // staging row / col chunk
    const int vkey = (sr & 15) << 2;
    const unsigned short* Kg =
        K + (size_t)(b * SS + ws * 1024 + sr) * EE + h * DD + sp;
    const unsigned short* Vg =
        Vt + ((size_t)bh * DD + sr) * SS + ws * 1024 + sp;

    // write one staged tile (regs -> LDS buffer)
    auto put = [&](unsigned short* Ks, unsigned short* Vs,
                   ushort8 k0, ushort8 k1, ushort8 v0, ushort8 v1) {
        *(ushort8*)&Ks[sr * LDK + sp] = k0;
        *(ushort8*)&Ks[sr * LDK + sp + 8] = k1;
        *(ush4*)&Vs[sr * 64 + ((sp +  0) ^ vkey)] =
            __builtin_shufflevector(v0, v0, 0, 1, 2, 3);
        *(ush4*)&Vs[sr * 64 + ((sp +  4) ^ vkey)] =
            __builtin_shufflevector(v0, v0, 4, 5, 6, 7);
        *(ush4*)&Vs[sr * 64 + ((sp +  8) ^ vkey)] =
            __builtin_shufflevector(v1, v1, 0, 1, 2, 3);
        *(ush4*)&Vs[sr * 64 + ((sp + 12) ^ vkey)] =
            __builtin_shufflevector(v1, v1, 4, 5, 6, 7);
    };

    // prologue: load tiles 0,1 -> reg sets 0,1; write tile 0 -> buf 0.
    ushort8 rk[2][2], rv[2][2];
    {
        const ushort8* gk0 = (const ushort8*)Kg;
        rk[0][0] = gk0[0]; rk[0][1] = gk0[1];
        const ushort8* gv0 = (const ushort8*)Vg;
        rv[0][0] = gv0[0]; rv[0][1] = gv0[1];
        const ushort8* gk1 = (const ushort8*)(Kg + (size_t)64 * EE);
        rk[1][0] = gk1[0]; rk[1][1] = gk1[1];
        const ushort8* gv1 = (const ushort8*)(Vg + 64);
        rv[1][0] = gv1[0]; rv[1][1] = gv1[1];
        put(Sb, Sb + 64 * LDK, rk[0][0], rk[0][1], rv[0][0], rv[0][1]);
        asm volatile("s_waitcnt lgkmcnt(0)" ::: "memory");
    }

#pragma unroll 2
    for (int it = 0; it < 16; ++it) {
        const unsigned short* Ks = Sb + (it & 1) * TSZ;
        const unsigned short* Vs = Ks + 64 * LDK;
        __builtin_amdgcn_s_barrier();   // buf[it&1] visible; prev reads done
        __builtin_amdgcn_sched_barrier(0);

        // issue loads tile it+2 -> set[it&1] (its old content, tile it, was
        // written to LDS at iter it-1). Wrap at tail -> dead reg loads only.
        {
            const int nit = (it + 2) & 15;
            const ushort8* gk = (const ushort8*)(Kg + (size_t)nit * 64 * EE);
            rk[it & 1][0] = gk[0]; rk[it & 1][1] = gk[1];
            const ushort8* gv = (const ushort8*)(Vg + nit * 64);
            rv[it & 1][0] = gv[0]; rv[it & 1][1] = gv[1];
        }

        // Fused per-K-slice: S^T (A = K rows sk=tt*16+c, B = Q rows) -> exp2
        // -> pack -> PV + lsum. Lane: P[sk=tt*16+q*4+r][qrow=c].
#pragma unroll
        for (int tt = 0; tt < 4; ++tt) {
            const short8 ka0 = *(const short8*)&Ks[(tt * 16 + c) * LDK + q * 8];
            const short8 ka1 = *(const short8*)&Ks[(tt * 16 + c) * LDK + 32 + q * 8];
            shortx4 pa[2];
#pragma unroll
            for (int g = 0; g < 2; ++g) {
                floatx4 s = {0.f, 0.f, 0.f, 0.f};
                s = MFMA32(ka0, qb[g][0], s);
                s = MFMA32(ka1, qb[g][1], s);
                union { unsigned int u[2]; shortx4 v; } pk;
                pk.u[0] = pkbf(__builtin_amdgcn_exp2f(s[0]),
                               __builtin_amdgcn_exp2f(s[1]));
                pk.u[1] = pkbf(__builtin_amdgcn_exp2f(s[2]),
                               __builtin_amdgcn_exp2f(s[3]));
                pa[g] = pk.v;
            }
            // O += P*V: A[m=qrow=c][k=q*4+j]; B[k][n=dv=c] from swizzled Vs.
#pragma unroll
            for (int nd = 0; nd < 4; ++nd) {
                const shortx4 vb = *(const shortx4*)
                    &Vs[(nd * 16 + c) * 64 + (((tt * 4 + q) ^ c) << 2)];
                o[0][nd] = MFMA16(pa[0], vb, o[0][nd]);
                o[1][nd] = MFMA16(pa[1], vb, o[1][nd]);
            }
            lacc[0] = MFMA16(pa[0], ones, lacc[0]);
            lacc[1] = MFMA16(pa[1], ones, lacc[1]);
        }

        __builtin_amdgcn_sched_barrier(0);  // keep writes (and their vmcnt
                                            // wait) below the compute
        // write tile it+1 (set[(it+1)&1]) -> buf[(it+1)&1]; compiler emits
        // counted vmcnt here -- tile it+2's loads stay in flight
        {
            unsigned short* Kn = Sb + ((it + 1) & 1) * TSZ;
            unsigned short* Vn = Kn + 64 * LDK;
            put(Kn, Vn, rk[(it + 1) & 1][0], rk[(it + 1) & 1][1],
                rv[(it + 1) & 1][0], rv[(it + 1) & 1][1]);
        }
        asm volatile("s_waitcnt lgkmcnt(0)" ::: "memory");
    }

    // ---- combine the two key halves (additive: no running max) ----
    __syncthreads();  // full drain; safe to reuse smem as Ob
    if (ws == 1) {
#pragma unroll
        for (int g = 0; g < 2; ++g) {
#pragma unroll
            for (int nd = 0; nd < 4; ++nd)
#pragma unroll
                for (int r = 0; r < 4; ++r)
                    Ob[(wq * 32 + g * 16 + q * 4 + r) * 66 + nd * 16 + c] =
                        o[g][nd][r];
            if (c == 0) {
#pragma unroll
                for (int r = 0; r < 4; ++r)
                    Ob[(wq * 32 + g * 16 + q * 4 + r) * 66 + 64] = lacc[g][r];
            }
        }
    }
    __syncthreads();
    if (ws == 0) {
#pragma unroll
        for (int g = 0; g < 2; ++g) {
            float linv[4];
#pragma unroll
            for (int r = 0; r < 4; ++r) {
                const int rr = wq * 32 + g * 16 + q * 4 + r;
#pragma unroll
                for (int nd = 0; nd < 4; ++nd)
                    o[g][nd][r] += Ob[rr * 66 + nd * 16 + c];
                linv[r] = __builtin_amdgcn_rcpf(lacc[g][r] + Ob[rr * 66 + 64]);
            }
            const int orow = b * SS + qt * 128 + wq * 32 + g * 16;
#pragma unroll
            for (int nd = 0; nd < 4; ++nd)
#pragma unroll
                for (int r = 0; r < 4; ++r)
                    O[(size_t)(orow + q * 4 + r) * EE + h * DD + nd * 16 + c] =
                        f2bf(o[g][nd][r] * linv[r]);
        }
    }
}

// ---------------------------------------------------------------------------
extern "C" void kernel_launch(void* const* d_in, const int* in_sizes, int n_in,
                              void* d_out, int out_size, void* d_ws, size_t ws_size,
                              hipStream_t stream)
{
    const float* x  = (const float*)d_in[0];
    const float* y  = (const float*)d_in[1];
    // d_in[2] = mask (int32) — faithfully ignored, as in the reference
    const float* Wq = (const float*)d_in[3];
    const float* bq = (const float*)d_in[4];
    const float* Wk = (const float*)d_in[5];
    const float* bk = (const float*)d_in[6];
    const float* Wv = (const float*)d_in[7];
    const float* bv = (const float*)d_in[8];
    const float* Wo = (const float*)d_in[9];
    const float* bo = (const float*)d_in[10];
    float* out = (float*)d_out;

    char* ws = (char*)d_ws;
    const size_t SZ = (size_t)BB * SS * EE * sizeof(unsigned short);  // 8 MiB
    const size_t WZ = (size_t)EE * EE * sizeof(unsigned short);       // 2 MiB
    unsigned short* xb  = (unsigned short*)(ws);
    unsigned short* yb  = (unsigned short*)(ws + SZ);
    unsigned short* Wqb = (unsigned short*)(ws + 2 * SZ);
    unsigned short* Wkb = (unsigned short*)(ws + 2 * SZ + WZ);
    unsigned short* Wvb = (unsigned short*)(ws + 2 * SZ + 2 * WZ);
    unsigned short* Wob = (unsigned short*)(ws + 2 * SZ + 3 * WZ);
    unsigned short* Qw  = (unsigned short*)(ws + 2 * SZ + 4 * WZ);
    unsigned short* Kw  = (unsigned short*)(ws + 3 * SZ + 4 * WZ);
    unsigned short* Vtw = (unsigned short*)(ws + 4 * SZ + 4 * WZ);
    unsigned short* Aw  = (unsigned short*)(ws + 5 * SZ + 4 * WZ);
    (void)ws_size; (void)in_sizes; (void)n_in; (void)out_size;

    k_cvt<<<dim3(3072), 256, 0, stream>>>(x, xb, y, yb, Wq, Wqb, Wk, Wkb,
                                          Wv, Wvb, Wo, Wob);
    k_gemm_qkv<<<dim3(24, 32), 256, 0, stream>>>(xb, yb, Wqb, bq, Wkb, bk, Wvb, bv,
                                                 Qw, Kw, Vtw);
    k_attn<<<dim3(32, 16), 512, 0, stream>>>(Qw, Kw, Vtw, Aw);
    k_gemm_out<<<dim3(8, 64), 256, 0, stream>>>(Aw, Wob, bo, out);
}